// Round 7
// baseline (141.498 us; speedup 1.0000x reference)
//
#include <hip/hip_runtime.h>
#include <math.h>

#define DIM 512
#define HID 8
#define LN_EPS 1e-5f

typedef float f32x4 __attribute__((ext_vector_type(4)));

// ---- DPP cross-lane helpers (VALU-speed, no LDS) ----
#define DPP_XOR1 0xB1   // quad_perm [1,0,3,2] : xor1
#define DPP_XOR2 0x4E   // quad_perm [2,3,0,1] : xor2
#define DPP_HM   0x141  // row_half_mirror (i^7 within 8): ==xor4 once 4-uniform
#define DPP_ROR8 0x128  // (i+8)&15 == i^8 : xor8 within 16
#define DPP_ROR4 0x124  // (i+4)&15 : ==xor4 (mod 8) on 8-periodic data

template <int CTRL>
__device__ __forceinline__ float dpp_movf(float v) {
    int r = __builtin_amdgcn_update_dpp(0, __builtin_bit_cast(int, v),
                                        CTRL, 0xF, 0xF, true);
    return __builtin_bit_cast(float, r);
}
template <int CTRL>
__device__ __forceinline__ float dpp_addf(float v) {
    return v + dpp_movf<CTRL>(v);
}
__device__ __forceinline__ float readlanef(float v, int lane) {
    return __builtin_bit_cast(float,
        __builtin_amdgcn_readlane(__builtin_bit_cast(int, v), lane));
}

// tanh-GELU via hardware exp2/rcp (abs err ~1e-3 vs exact; threshold 0.166)
__device__ __forceinline__ float gelu_fast(float v) {
    const float C = 0.044715f;
    const float K = 2.30258819f; // 2*0.7978845608*log2(e)
    float v2 = v * v;
    float t  = v * fmaf(C, v2, 1.0f);
    float e  = __builtin_amdgcn_exp2f(K * t);
    float r  = __builtin_amdgcn_rcpf(e + 1.0f);
    return fmaf(-v, r, v);
}

// full wave sum of a scalar -> SGPR-broadcast value
__device__ __forceinline__ float wave_sum(float v) {
    v = dpp_addf<DPP_XOR1>(v);
    v = dpp_addf<DPP_XOR2>(v);
    v = dpp_addf<DPP_HM>(v);
    v = dpp_addf<DPP_ROR8>(v);
    return (readlanef(v, 0) + readlanef(v, 16))
         + (readlanef(v, 32) + readlanef(v, 48));
}

// reduce 8 partials; every lane ends with wave-complete sum of partial[lane&7]
__device__ __forceinline__ float reduce8(float ph[8], int lj) {
#pragma unroll
    for (int j = 0; j < 8; ++j) ph[j] = dpp_addf<DPP_XOR1>(ph[j]);
#pragma unroll
    for (int j = 0; j < 8; ++j) ph[j] = dpp_addf<DPP_XOR2>(ph[j]);
#pragma unroll
    for (int j = 0; j < 8; ++j) ph[j] = dpp_addf<DPP_HM>(ph[j]);
    float sel = ph[0];
    sel = (lj == 1) ? ph[1] : sel;
    sel = (lj == 2) ? ph[2] : sel;
    sel = (lj == 3) ? ph[3] : sel;
    sel = (lj == 4) ? ph[4] : sel;
    sel = (lj == 5) ? ph[5] : sel;
    sel = (lj == 6) ? ph[6] : sel;
    sel = (lj == 7) ? ph[7] : sel;
    sel = dpp_addf<DPP_ROR8>(sel);
    sel += __shfl_xor(sel, 16, 64);
    sel += __shfl_xor(sel, 32, 64);
    return sel;
}

__device__ __forceinline__ void load8(float* dst, const float* __restrict__ src) {
    const f32x4* p = reinterpret_cast<const f32x4*>(src);
    f32x4 a = p[0];
    f32x4 b = p[1];
    dst[0] = a.x; dst[1] = a.y; dst[2] = a.z; dst[3] = a.w;
    dst[4] = b.x; dst[5] = b.y; dst[6] = b.z; dst[7] = b.w;
}

// No occupancy attributes, no asm pins: let the allocator pick (~110 VGPR,
// reloading weights from hot L1 per row). TLP via a 4x bigger grid is what
// hides latency — R4's grid (2048 waves) capped occupancy at 25%.
__global__ __launch_bounds__(256)
void mlp_fused_kernel(const float* __restrict__ x,
                      const float* __restrict__ w1,
                      const float* __restrict__ b1,
                      const float* __restrict__ w2,
                      const float* __restrict__ b2,
                      const float* __restrict__ gamma,
                      const float* __restrict__ beta,
                      float* __restrict__ out,
                      int nrows, int rows_per_wave) {
    const int lane  = threadIdx.x & 63;
    const int wav   = threadIdx.x >> 6;
    const int wgid  = blockIdx.x * 4 + wav;
    const int dbase = lane * 8;
    const int lj    = lane & 7;

    const int r0 = wgid * rows_per_wave;
    if (r0 >= nrows) return;
    int r1 = r0 + rows_per_wave;
    if (r1 > nrows) r1 = nrows;

    // ---- startup: load + fold weights (gamma/beta die after this) ----
    float gm[8], bt[8];
    load8(gm, gamma + dbase);
    load8(bt, beta  + dbase);

    float w1g[64];                 // w1g[j*8+k] = w1[j, dbase+k] * gamma[dbase+k]
    float w1sp[8], c1p[8];
#pragma unroll
    for (int j = 0; j < 8; ++j) { w1sp[j] = 0.f; c1p[j] = 0.f; }
#pragma unroll
    for (int j = 0; j < 8; ++j) {
        float raw[8];
        load8(raw, w1 + j * DIM + dbase);
#pragma unroll
        for (int k = 0; k < 8; ++k) {
            c1p[j] = fmaf(bt[k], raw[k], c1p[j]);
            float wg = raw[k] * gm[k];
            w1g[j * 8 + k] = wg;
            w1sp[j] += wg;
        }
    }
    const float W1s = reduce8(w1sp, lj);          // Sum_d w1g[lj, d]
    const float b1e = b1[lj] + reduce8(c1p, lj);  // b1 + Sum_d beta_d*w1[lj,d]

    float w2p[64];                 // w2p[k*8+t] = w2[dbase+k, lj^t]
#pragma unroll
    for (int k = 0; k < 8; ++k)
#pragma unroll
        for (int t = 0; t < 8; ++t)
            w2p[k * 8 + t] = w2[(size_t)(dbase + k) * HID + (lj ^ t)];

    float b2r[8];
    load8(b2r, b2 + dbase);

    // ---- prefetch first row ----
    float xv[8];
    load8(xv, x + (size_t)r0 * DIM + dbase);

    for (int r = r0; r < r1; ++r) {
        // prefetch next row (clamped; branchless)
        float xn[8];
        const int rn = (r + 1 < r1) ? (r + 1) : r;
        load8(xn, x + (size_t)rn * DIM + dbase);

        // ---- local partials ----
        float s = 0.f, q = 0.f;
#pragma unroll
        for (int k = 0; k < 8; ++k) { s += xv[k]; q = fmaf(xv[k], xv[k], q); }

        float ph[8];
#pragma unroll
        for (int j = 0; j < 8; ++j) {
            float a = 0.f;
#pragma unroll
            for (int k = 0; k < 8; ++k)
                a = fmaf(xv[k], w1g[j * 8 + k], a);
            ph[j] = a;
        }

        // ---- reductions ----
        const float sw = wave_sum(s);
        const float qw = wave_sum(q);
        const float Hw = reduce8(ph, lj);

        const float mu  = sw * (1.0f / DIM);
        const float var = qw * (1.0f / DIM) - mu * mu;
        const float rs  = rsqrtf(var + LN_EPS);

        // h[lj] = rs*(Hw - mu*W1s) + b1e ; one gelu per lane
        const float h = gelu_fast(fmaf(rs, fmaf(-mu, W1s, Hw), b1e));

        // ---- broadcast via DPP: hj[t] = H[(lane^t)&7] ----
        float hj[8];
        hj[0] = h;
        hj[1] = dpp_movf<DPP_XOR1>(hj[0]);
        hj[2] = dpp_movf<DPP_XOR2>(hj[0]);
        hj[3] = dpp_movf<DPP_XOR2>(hj[1]);
        hj[4] = dpp_movf<DPP_ROR4>(hj[0]);
        hj[5] = dpp_movf<DPP_ROR4>(hj[1]);
        hj[6] = dpp_movf<DPP_ROR4>(hj[2]);
        hj[7] = dpp_movf<DPP_ROR4>(hj[3]);

        // ---- o[d] = gelu(sum_t hj[t]*w2p[d,t] + b2[d]) + x[d] ----
        f32x4 o0, o1;
#pragma unroll
        for (int k = 0; k < 8; ++k) {
            float o = b2r[k];
#pragma unroll
            for (int t = 0; t < 8; ++t)
                o = fmaf(hj[t], w2p[k * 8 + t], o);
            float val = gelu_fast(o) + xv[k];
            if (k < 4) o0[k] = val; else o1[k - 4] = val;
        }

        float* po = out + (size_t)r * DIM + dbase;
        __builtin_nontemporal_store(o0, reinterpret_cast<f32x4*>(po));
        __builtin_nontemporal_store(o1, reinterpret_cast<f32x4*>(po) + 1);

#pragma unroll
        for (int k = 0; k < 8; ++k) xv[k] = xn[k];
    }
}

extern "C" void kernel_launch(void* const* d_in, const int* in_sizes, int n_in,
                              void* d_out, int out_size, void* d_ws, size_t ws_size,
                              hipStream_t stream) {
    const float* x     = (const float*)d_in[0];
    const float* w1    = (const float*)d_in[1];
    const float* b1    = (const float*)d_in[2];
    const float* w2    = (const float*)d_in[3];
    const float* b2    = (const float*)d_in[4];
    const float* gamma = (const float*)d_in[5];
    const float* beta  = (const float*)d_in[6];
    float* out = (float*)d_out;

    const int nrows  = in_sizes[0] / DIM;         // 131072
    const int blocks = 2048;                      // 4 waves each = 8192 waves
    const int total_waves = blocks * 4;
    const int rows_per_wave = (nrows + total_waves - 1) / total_waves;  // 16

    mlp_fused_kernel<<<blocks, 256, 0, stream>>>(
        x, w1, b1, w2, b2, gamma, beta, out, nrows, rows_per_wave);
}